// Round 7
// baseline (212.707 us; speedup 1.0000x reference)
//
#include <hip/hip_runtime.h>
#include <stdint.h>

typedef unsigned int u32;
typedef unsigned long long u64;

#define F_UPPER 0.4f
#define F_LOWER 0.1f
#define MAX_POS 2048
#define L_SZ 65536
#define M_SZ 512
#define C_SZ 21
#define NBINS 8192
#define BIN_CAP 32
#define OVF_CAP 1024
#define FLG_AGG (1ull << 62)
#define FLG_PRE (2ull << 62)
#define FLG_MASK (3ull << 62)

struct State {
  double sum_pos_ce;
  double sum_neg_ce;
  double bbox_sum;
  int num_pos;
  int num_neg;
  u32 done;
  u32 _pad;
  u64 thresh;
};

__device__ __forceinline__ float area_fn(const float4 a) {
#pragma clang fp contract(off)
  return (a.z - a.x + 1.0f) * (a.w - a.y + 1.0f);
}

// IoU, op order identical to prior rounds (absmax 0 preserved).
__device__ __forceinline__ float iou_rcp(const float4 a, const float4 b, float a1, float a2) {
#pragma clang fp contract(off)
  float iw = fminf(a.z, b.z) - fmaxf(a.x, b.x) + 1.0f;
  iw = fmaxf(iw, 0.0f);
  float ih = fminf(a.w, b.w) - fmaxf(a.y, b.y) + 1.0f;
  ih = fmaxf(ih, 0.0f);
  float inter = iw * ih;
  return inter * __builtin_amdgcn_rcpf(a1 + a2 - inter);
}

__device__ __forceinline__ float sl1(float d) {
#pragma clang fp contract(off)
  float ad = fabsf(d);
  return (ad < 0.01f) ? (50.0f * d * d) : (ad - 0.005f);
}

__device__ __forceinline__ u32 rotl(u32 x, int d) { return (x << d) | (x >> (32 - d)); }

// JAX threefry2x32, key=(0,42); counts = iota(L) split in halves.
__device__ u32 threefry_bits(u32 i, u32 H) {
  u32 x0, x1; bool hi;
  if (i < H) { x0 = i;     x1 = i + H; hi = false; }
  else       { x0 = i - H; x1 = i;     hi = true;  }
  const u32 ks0 = 0u, ks1 = 42u;
  const u32 ks2 = ks0 ^ ks1 ^ 0x1BD11BDAu;
  x0 += ks0; x1 += ks1;
#define RND(r) { x0 += x1; x1 = rotl(x1, r); x1 ^= x0; }
  RND(13) RND(15) RND(26) RND(6)   x0 += ks1; x1 += ks2 + 1u;
  RND(17) RND(29) RND(16) RND(24)  x0 += ks2; x1 += ks0 + 2u;
  RND(13) RND(15) RND(26) RND(6)   x0 += ks0; x1 += ks1 + 3u;
  RND(17) RND(29) RND(16) RND(24)  x0 += ks1; x1 += ks2 + 4u;
  RND(13) RND(15) RND(26) RND(6)   x0 += ks2; x1 += ks0 + 5u;
#undef RND
  return hi ? x1 : x0;
}

// Device-scope atomic loads (cross-XCD visibility, guide §6 G16).
__device__ __forceinline__ u32 ald32(const u32* p) {
  return __hip_atomic_load(p, __ATOMIC_ACQUIRE, __HIP_MEMORY_SCOPE_AGENT);
}
__device__ __forceinline__ u64 ald64(const u64* p) {
  return __hip_atomic_load(p, __ATOMIC_ACQUIRE, __HIP_MEMORY_SCOPE_AGENT);
}
__device__ __forceinline__ int aldi(const int* p) {
  return __hip_atomic_load(p, __ATOMIC_ACQUIRE, __HIP_MEMORY_SCOPE_AGENT);
}
__device__ __forceinline__ double aldd(const double* p) {
  return __hip_atomic_load(p, __ATOMIC_ACQUIRE, __HIP_MEMORY_SCOPE_AGENT);
}

// ======== kA: ROI + single-pass register-microtiled IoU. 1024 blocks, 64 preds/block.
// Thread layout: pg = tid&15 owns preds 4*pg..+3 (in regs); gg = tid>>4 owns gts 32*gg..+31.
__global__ void __launch_bounds__(256) kA(const float* __restrict__ rois,
    const float* __restrict__ scores, const float* __restrict__ deltas,
    const float4* __restrict__ gtb,
    float4* __restrict__ pred, float* __restrict__ lse,
    u64* __restrict__ rowkey, u64* __restrict__ gkey) {
  __shared__ float  ssc[64 * C_SZ];
  __shared__ float  sro[64 * 5];
  __shared__ float4 sg[M_SZ];
  __shared__ float  ga[M_SZ];
  __shared__ u64    scol[M_SZ];
  __shared__ u64    srow[64];
  __shared__ float4 spred[64];
  __shared__ float  sarea[64];
  const int tid = threadIdx.x;
  const int pbase = blockIdx.x << 6;
  for (int k = tid; k < 64 * C_SZ; k += 256) ssc[k] = scores[(size_t)pbase * C_SZ + k];
  for (int k = tid; k < 64 * 5; k += 256)    sro[k] = rois[(size_t)pbase * 5 + k];
  for (int j = tid; j < M_SZ; j += 256) {
    float4 g = gtb[j]; sg[j] = g; ga[j] = area_fn(g); scol[j] = 0ull;
  }
  if (tid < 64) srow[tid] = 0ull;
  __syncthreads();
  if (tid < 64) {
    const int i = pbase + tid;
    const float* sr = ssc + tid * C_SZ;
    float mx = sr[0]; int mi = 0;
    for (int j = 1; j < C_SZ; ++j) { float v = sr[j]; if (v > mx) { mx = v; mi = j; } }
    float s = 0.0f;
    for (int j = 0; j < C_SZ; ++j) s += expf(sr[j] - mx);
    lse[i] = mx + logf(s);
    // 16B-aligned gather: (84*i + 4*mi) floats is a multiple of 4 floats.
    float4 d = *(const float4*)(deltas + (size_t)i * (4 * C_SZ) + 4 * mi);
    const float* r = sro + tid * 5;
    float4 pb;
    pb.x = r[1] + d.x; pb.y = r[2] + d.y; pb.z = r[3] + d.z; pb.w = r[4] + d.w;
    spred[tid] = pb; sarea[tid] = area_fn(pb);
    pred[i] = pb;
  }
  __syncthreads();
  // --- micro-tile: 4 preds (regs) x 32 gts per thread; each IoU computed ONCE ---
  const int pg = tid & 15;
  const int gg = tid >> 4;
  const int p0 = pg << 2;
  const float4 pb0 = spred[p0 + 0], pb1 = spred[p0 + 1];
  const float4 pb2 = spred[p0 + 2], pb3 = spred[p0 + 3];
  const float pa0 = sarea[p0 + 0], pa1 = sarea[p0 + 1];
  const float pa2 = sarea[p0 + 2], pa3 = sarea[p0 + 3];
  const u32 cl0 = 0xFFFFFFFFu - (u32)(pbase + p0 + 0);
  const u32 cl1 = 0xFFFFFFFFu - (u32)(pbase + p0 + 1);
  const u32 cl2 = 0xFFFFFFFFu - (u32)(pbase + p0 + 2);
  const u32 cl3 = 0xFFFFFFFFu - (u32)(pbase + p0 + 3);
  u64 rk0 = 0ull, rk1 = 0ull, rk2 = 0ull, rk3 = 0ull;
  const int jbase = gg << 5;
  const int joff = (pg << 1);  // stagger: 16 pred-group threads hit 16 distinct j
#pragma unroll 2
  for (int jj = 0; jj < 32; ++jj) {
    const int j = jbase + ((jj + joff) & 31);
    const float4 gb = sg[j];
    const float gba = ga[j];
    const u32 lowj = 0xFFFFFFFFu - (u32)j;
    float v0 = iou_rcp(pb0, gb, pa0, gba);
    float v1 = iou_rcp(pb1, gb, pa1, gba);
    float v2 = iou_rcp(pb2, gb, pa2, gba);
    float v3 = iou_rcp(pb3, gb, pa3, gba);
    u64 k0 = ((u64)__float_as_uint(v0) << 32) | lowj; if (k0 > rk0) rk0 = k0;
    u64 k1 = ((u64)__float_as_uint(v1) << 32) | lowj; if (k1 > rk1) rk1 = k1;
    u64 k2 = ((u64)__float_as_uint(v2) << 32) | lowj; if (k2 > rk2) rk2 = k2;
    u64 k3 = ((u64)__float_as_uint(v3) << 32) | lowj; if (k3 > rk3) rk3 = k3;
    // col max among the 4 owned preds; equal-iou tie -> smaller pred idx (larger low32)
    u64 c = ((u64)__float_as_uint(v0) << 32) | cl0;
    u64 t1 = ((u64)__float_as_uint(v1) << 32) | cl1; if (t1 > c) c = t1;
    u64 t2 = ((u64)__float_as_uint(v2) << 32) | cl2; if (t2 > c) c = t2;
    u64 t3 = ((u64)__float_as_uint(v3) << 32) | cl3; if (t3 > c) c = t3;
    atomicMax(&scol[j], c);
  }
  atomicMax(&srow[p0 + 0], rk0);
  atomicMax(&srow[p0 + 1], rk1);
  atomicMax(&srow[p0 + 2], rk2);
  atomicMax(&srow[p0 + 3], rk3);
  __syncthreads();
  if (tid < 64) rowkey[pbase + tid] = srow[tid];
  for (int j = tid; j < M_SZ; j += 256) atomicMax(&gkey[j], scol[j]);
}

// ======== kB: scat + match + pos CE + bucket-store + lookback scan + compaction
//             + (block 255) negative selection. 256 blocks.
__global__ void __launch_bounds__(256) kB(const u64* __restrict__ rowkey,
    const u64* __restrict__ gkey, const int* __restrict__ gtc,
    const float* __restrict__ scores, const float* __restrict__ lse,
    const float4* __restrict__ pred, const float4* __restrict__ gtb,
    u32* __restrict__ neg_u, u32* __restrict__ hist0, u64* __restrict__ bins,
    u64* __restrict__ scanst, float4* __restrict__ pp, float4* __restrict__ gp,
    State* st) {
  __shared__ int sscat[256];   // reused as scan buffer in selection
  __shared__ int swsum[4], sncnt[4];
  __shared__ double sdacc[4];
  __shared__ int s_bpref, s_np, s_nn;
  __shared__ int s_d, s_kk, s_cnt;
  __shared__ u32 s_ovf;
  __shared__ u64 sth;
  __shared__ u64 scand[OVF_CAP];
  const int tid = threadIdx.x, b = blockIdx.x;
  const int lane = tid & 63, wid = tid >> 6;
  // ---- phase 1: rebuild scatter table for this block's pred range ----
  sscat[tid] = -1;
  __syncthreads();
  for (int g = tid; g < M_SZ; g += 256) {
    u64 key = gkey[g];
    int pidx = (int)(0xFFFFFFFFu - (u32)key);
    if ((pidx >> 8) == b) atomicMax(&sscat[pidx & 255], g);  // dup idx_g: last (max g) wins
  }
  __syncthreads();
  // ---- phase 2: match + per-i work ----
  const int i = (b << 8) + tid;
  u64 rk = rowkey[i];
  float best = __uint_as_float((u32)(rk >> 32));
  int idxp = (int)(0xFFFFFFFFu - (u32)rk);
  int m;
  if (best < F_LOWER) m = -2;
  else {
    int s = sscat[tid];
    m = (s >= 0) ? s : ((best >= F_UPPER) ? idxp : -1);
  }
  u32 ub = threefry_bits((u32)i, L_SZ >> 1) >> 9;
  atomicExch(&neg_u[i], (m == -2) ? ub : 0xFFFFFFFFu);  // device-scope store
  float ce = 0.0f;
  if (m >= 0) {
    ce = lse[i] - scores[(size_t)i * C_SZ + gtc[m]];
  } else if (m == -2) {
    u32 bin = ub >> 10;
    u32 pos = atomicAdd(&hist0[bin], 1u);
    if (pos < BIN_CAP) atomicExch(&bins[(size_t)bin * BIN_CAP + pos], ((u64)ub << 16) | (u32)i);
  }
  u64 balp = __ballot(m >= 0);
  u64 baln = __ballot(m == -2);
  double acc = (double)ce;
  for (int off = 32; off > 0; off >>= 1) acc += __shfl_down(acc, off, 64);
  if (lane == 0) { swsum[wid] = __popcll(balp); sncnt[wid] = __popcll(baln); sdacc[wid] = acc; }
  __syncthreads();
  // ---- phase 3: publish + decoupled lookback (tid 0) ----
  if (tid == 0) {
    int cp = swsum[0] + swsum[1] + swsum[2] + swsum[3];
    int cn = sncnt[0] + sncnt[1] + sncnt[2] + sncnt[3];
    atomicAdd(&st->num_pos, cp);
    atomicAdd(&st->num_neg, cn);
    atomicAdd(&st->sum_pos_ce, sdacc[0] + sdacc[1] + sdacc[2] + sdacc[3]);
    u64 run = 0;
    if (b == 0) {
      __hip_atomic_store(&scanst[0], FLG_PRE | (u64)cp, __ATOMIC_RELEASE, __HIP_MEMORY_SCOPE_AGENT);
    } else {
      __hip_atomic_store(&scanst[b], FLG_AGG | (u64)cp, __ATOMIC_RELEASE, __HIP_MEMORY_SCOPE_AGENT);
      int x = b - 1;
      while (true) {
        u64 v = __hip_atomic_load(&scanst[x], __ATOMIC_ACQUIRE, __HIP_MEMORY_SCOPE_AGENT);
        u64 f = v & FLG_MASK;
        if (f == 0ull) { __builtin_amdgcn_s_sleep(1); continue; }
        run += v & ~FLG_MASK;
        if (f == FLG_PRE) break;
        --x;
      }
      __hip_atomic_store(&scanst[b], FLG_PRE | (run + (u64)cp), __ATOMIC_RELEASE, __HIP_MEMORY_SCOPE_AGENT);
    }
    s_bpref = (int)run;
    if (b == 255) {
      s_np = (int)run + cp;  // total positives (deterministic)
      s_nn = aldi(&st->num_neg);  // all blocks published before our lookback completed
    }
  }
  __syncthreads();
  // ---- phase 4: index-ordered compaction ----
  const int bpref = s_bpref;
  if (bpref < MAX_POS) {  // block-uniform
    int flag = (m >= 0) ? 1 : 0;
    int incl = flag;
#pragma unroll
    for (int off = 1; off < 64; off <<= 1) {
      int v = __shfl_up(incl, off, 64);
      if (lane >= off) incl += v;
    }
    if (lane == 63) swsum[wid] = incl;
    __syncthreads();
    int wbase = 0;
    for (int w = 0; w < wid; ++w) wbase += swsum[w];
    int rank = bpref + wbase + incl - flag;
    if (flag && rank < MAX_POS) { pp[rank] = pred[i]; gp[rank] = gtb[m]; }
  }
  // ---- phase 5: negative selection (block 255 only) ----
  if (b != 255) return;
  __syncthreads();
  const int np = s_np, nn = s_nn;  // bg_num = round(np * 1.0) = np
  if (np >= nn) {
    if (tid == 0) st->thresh = ~0ull;  // select all negatives
    return;
  }
  u32 loc[32]; int tsum = 0;
#pragma unroll
  for (int r = 0; r < 32; ++r) { loc[r] = ald32(&hist0[tid * 32 + r]); tsum += (int)loc[r]; }
  sscat[tid] = tsum;
  __syncthreads();
  for (int off = 1; off < 256; off <<= 1) {
    int v = (tid >= off) ? sscat[tid - off] : 0;
    __syncthreads();
    sscat[tid] += v;
    __syncthreads();
  }
  int incl2 = sscat[tid], excl2 = incl2 - tsum;
  if (np >= excl2 && np < incl2) {
    int kk = np - excl2; int d = 0, c = 0;
#pragma unroll
    for (int r = 0; r < 32; ++r) {
      if (kk < (int)loc[r]) { d = tid * 32 + r; c = (int)loc[r]; break; }
      kk -= (int)loc[r];
    }
    s_d = d; s_kk = kk; s_cnt = c;
  }
  if (tid == 0) s_ovf = 0;
  __syncthreads();
  const int d = s_d, kk = s_kk, cnt = s_cnt;
  if (cnt <= BIN_CAP) {
    if (tid < cnt) scand[tid] = ald64(&bins[(size_t)d * BIN_CAP + tid]);
    __syncthreads();
    if (tid < cnt) {
      u64 key = scand[tid];
      int rank = 0;
      for (int u = 0; u < cnt; ++u) rank += (scand[u] < key) ? 1 : 0;
      if (rank == kk) sth = key;  // keys unique -> single writer
    }
  } else {
    // fallback (Poisson(8) > 32: ~1e-12 per bin): sweep neg_u for bin-d keys
    for (int t = tid; t < L_SZ; t += 256) {
      u32 u = ald32(&neg_u[t]);
      if (u != 0xFFFFFFFFu && (int)(u >> 10) == d) {
        u32 pos = atomicAdd(&s_ovf, 1u);
        if (pos < OVF_CAP) scand[pos] = ((u64)u << 16) | (u32)t;
      }
    }
    __syncthreads();
    int c2 = (int)s_ovf; if (c2 > OVF_CAP) c2 = OVF_CAP;
    for (int t = tid; t < c2; t += 256) {
      u64 key = scand[t];
      int rank = 0;
      for (int u = 0; u < c2; ++u) rank += (scand[u] < key) ? 1 : 0;
      if (rank == kk) sth = key;
    }
  }
  __syncthreads();
  if (tid == 0) st->thresh = sth;  // select keys strictly below the rank-bg_num key
}

// ======== kC: neg CE (all 256 blocks) + pair smooth-L1 (blocks 0..127) + final write.
__global__ void __launch_bounds__(256) kC(const u32* __restrict__ neg_u,
    const float* __restrict__ scores, const float* __restrict__ lse,
    const float4* __restrict__ pp, const float4* __restrict__ gp,
    State* st, float* __restrict__ out) {
  __shared__ float4 sj[128];
  __shared__ double sdacc[4];
  const int tid = threadIdx.x, b = blockIdx.x;
  const int lane = tid & 63, wid = tid >> 6;
  const u64 thresh = st->thresh;
  const int i = (b << 8) + tid;
  u32 u = neg_u[i];
  double acc = 0.0;
  if (u != 0xFFFFFFFFu) {
    u64 key = ((u64)u << 16) | (u32)i;
    if (key < thresh)
      acc = (double)(lse[i] - scores[(size_t)i * C_SZ + (C_SZ - 1)]);  // BACKGROUND=20
  }
  for (int off = 32; off > 0; off >>= 1) acc += __shfl_down(acc, off, 64);
  if (lane == 0) sdacc[wid] = acc;
  __syncthreads();
  if (tid == 0) atomicAdd(&st->sum_neg_ce, sdacc[0] + sdacc[1] + sdacc[2] + sdacc[3]);
  __syncthreads();
  if (b < 128) {
    int n = st->num_pos; if (n > MAX_POS) n = MAX_POS;
    const int jb = (b & 15) << 7;
    if (tid < 128) {
      int j = jb + tid;
      sj[tid] = (j < n) ? pp[j] : make_float4(0.f, 0.f, 0.f, 0.f);
    }
    __syncthreads();
    const int ii = ((b >> 4) << 8) + tid;
    double pacc = 0.0;
    if (ii < n) {
      float4 g = gp[ii];
      int jend = n - jb; if (jend > 128) jend = 128;
      for (int j = 0; j < jend; ++j) {
        float4 p4 = sj[j];
        pacc += (double)sl1(p4.x - g.x);
        pacc += (double)sl1(p4.y - g.y);
        pacc += (double)sl1(p4.z - g.z);
        pacc += (double)sl1(p4.w - g.w);
      }
    }
    for (int off = 32; off > 0; off >>= 1) pacc += __shfl_down(pacc, off, 64);
    if (lane == 0) sdacc[wid] = pacc;
    __syncthreads();
    if (tid == 0) atomicAdd(&st->bbox_sum, sdacc[0] + sdacc[1] + sdacc[2] + sdacc[3]);
  }
  if (tid == 0) {
    __threadfence();
    u32 dn = atomicAdd(&st->done, 1u);
    if (dn == 255) {  // last block: all contributions at coherent point
      int np = aldi(&st->num_pos), nn = aldi(&st->num_neg);
      double spc = aldd(&st->sum_pos_ce), snc = aldd(&st->sum_neg_ce);
      double bbs = aldd(&st->bbox_sum);
      int nsel = (np < nn) ? np : nn;
      double wsum = (double)(np + nsel);
      out[0] = (float)((spc + snc) / wsum);
      out[1] = (float)bbs;
    }
  }
}

// ---------- launch ----------

extern "C" void kernel_launch(void* const* d_in, const int* in_sizes, int n_in,
                              void* d_out, int out_size, void* d_ws, size_t ws_size,
                              hipStream_t stream) {
  const float* rois   = (const float*)d_in[0];
  const float* scores = (const float*)d_in[1];
  const float* deltas = (const float*)d_in[2];
  const float4* gtb   = (const float4*)d_in[3];
  const int*   gtc    = (const int*)d_in[4];
  float* out = (float*)d_out;

  char* w = (char*)d_ws;
  // zero-init region: State | gkey | hist0 | scanst (~39KB memset)
  State* st    = (State*)w;   w += 256;
  u64* gkey    = (u64*)w;     w += (size_t)M_SZ * 8;
  u32* hist0   = (u32*)w;     w += (size_t)NBINS * 4;
  u64* scanst  = (u64*)w;     w += 256 * 8;
  char* zero_end = w;
  // no-init scratch
  u64* bins    = (u64*)w;     w += (size_t)NBINS * BIN_CAP * 8;
  float4* pred = (float4*)w;  w += (size_t)L_SZ * 16;
  float* lse   = (float*)w;   w += (size_t)L_SZ * 4;
  u64* rowkey  = (u64*)w;     w += (size_t)L_SZ * 8;
  u32* neg_u   = (u32*)w;     w += (size_t)L_SZ * 4;
  float4* pp   = (float4*)w;  w += (size_t)MAX_POS * 16;
  float4* gp   = (float4*)w;  w += (size_t)MAX_POS * 16;

  hipMemsetAsync(d_ws, 0, (size_t)(zero_end - (char*)d_ws), stream);

  kA<<<L_SZ / 64, 256, 0, stream>>>(rois, scores, deltas, gtb, pred, lse, rowkey, gkey);
  kB<<<L_SZ / 256, 256, 0, stream>>>(rowkey, gkey, gtc, scores, lse, pred, gtb,
                                     neg_u, hist0, bins, scanst, pp, gp, st);
  kC<<<L_SZ / 256, 256, 0, stream>>>(neg_u, scores, lse, pp, gp, st, out);
}

// Round 8
// 175.134 us; speedup vs baseline: 1.2145x; 1.2145x over previous
//
#include <hip/hip_runtime.h>
#include <stdint.h>

typedef unsigned int u32;
typedef unsigned long long u64;

#define F_UPPER 0.4f
#define F_LOWER 0.1f
#define MAX_POS 2048
#define L_SZ 65536
#define M_SZ 512
#define C_SZ 21
#define NBINS 8192
#define BIN_CAP 32
#define OVF_CAP 1024
#define FLG_AGG (1ull << 62)
#define FLG_MASK (3ull << 62)

struct State {
  double sum_pos_ce;
  double sum_neg_ce;
  double bbox_sum;
  int num_pos;
  int num_neg;
  u32 done;
  u32 _pad;
  u64 thresh;
};

__device__ __forceinline__ float area_fn(const float4 a) {
#pragma clang fp contract(off)
  return (a.z - a.x + 1.0f) * (a.w - a.y + 1.0f);
}

// IoU, op order identical to prior rounds (absmax 0 preserved).
__device__ __forceinline__ float iou_rcp(const float4 a, const float4 b, float a1, float a2) {
#pragma clang fp contract(off)
  float iw = fminf(a.z, b.z) - fmaxf(a.x, b.x) + 1.0f;
  iw = fmaxf(iw, 0.0f);
  float ih = fminf(a.w, b.w) - fmaxf(a.y, b.y) + 1.0f;
  ih = fmaxf(ih, 0.0f);
  float inter = iw * ih;
  return inter * __builtin_amdgcn_rcpf(a1 + a2 - inter);
}

__device__ __forceinline__ float sl1(float d) {
#pragma clang fp contract(off)
  float ad = fabsf(d);
  return (ad < 0.01f) ? (50.0f * d * d) : (ad - 0.005f);
}

__device__ __forceinline__ u32 rotl(u32 x, int d) { return (x << d) | (x >> (32 - d)); }

// JAX threefry2x32, key=(0,42); counts = iota(L) split in halves.
__device__ u32 threefry_bits(u32 i, u32 H) {
  u32 x0, x1; bool hi;
  if (i < H) { x0 = i;     x1 = i + H; hi = false; }
  else       { x0 = i - H; x1 = i;     hi = true;  }
  const u32 ks0 = 0u, ks1 = 42u;
  const u32 ks2 = ks0 ^ ks1 ^ 0x1BD11BDAu;
  x0 += ks0; x1 += ks1;
#define RND(r) { x0 += x1; x1 = rotl(x1, r); x1 ^= x0; }
  RND(13) RND(15) RND(26) RND(6)   x0 += ks1; x1 += ks2 + 1u;
  RND(17) RND(29) RND(16) RND(24)  x0 += ks2; x1 += ks0 + 2u;
  RND(13) RND(15) RND(26) RND(6)   x0 += ks0; x1 += ks1 + 3u;
  RND(17) RND(29) RND(16) RND(24)  x0 += ks1; x1 += ks2 + 4u;
  RND(13) RND(15) RND(26) RND(6)   x0 += ks2; x1 += ks0 + 5u;
#undef RND
  return hi ? x1 : x0;
}

// Device-scope atomic loads (cross-XCD visibility, guide §6 G16).
__device__ __forceinline__ u32 ald32(const u32* p) {
  return __hip_atomic_load(p, __ATOMIC_ACQUIRE, __HIP_MEMORY_SCOPE_AGENT);
}
__device__ __forceinline__ u64 ald64(const u64* p) {
  return __hip_atomic_load(p, __ATOMIC_ACQUIRE, __HIP_MEMORY_SCOPE_AGENT);
}
__device__ __forceinline__ int aldi(const int* p) {
  return __hip_atomic_load(p, __ATOMIC_ACQUIRE, __HIP_MEMORY_SCOPE_AGENT);
}
__device__ __forceinline__ double aldd(const double* p) {
  return __hip_atomic_load(p, __ATOMIC_ACQUIRE, __HIP_MEMORY_SCOPE_AGENT);
}

// ======== kA: ROI + single-pass register-microtiled IoU. 1024 blocks, 64 preds/block.
// Thread layout: pg = tid&15 owns preds 4*pg..+3 (in regs); gg = tid>>4 owns gts 32*gg..+31.
__global__ void __launch_bounds__(256) kA(const float* __restrict__ rois,
    const float* __restrict__ scores, const float* __restrict__ deltas,
    const float4* __restrict__ gtb,
    float4* __restrict__ pred, float* __restrict__ lse,
    u64* __restrict__ rowkey, u64* __restrict__ gkey) {
  __shared__ float  ssc[64 * C_SZ];
  __shared__ float  sro[64 * 5];
  __shared__ float4 sg[M_SZ];
  __shared__ float  ga[M_SZ];
  __shared__ u64    scol[M_SZ];
  __shared__ u64    srow[64];
  __shared__ float4 spred[64];
  __shared__ float  sarea[64];
  const int tid = threadIdx.x;
  const int pbase = blockIdx.x << 6;
  for (int k = tid; k < 64 * C_SZ; k += 256) ssc[k] = scores[(size_t)pbase * C_SZ + k];
  for (int k = tid; k < 64 * 5; k += 256)    sro[k] = rois[(size_t)pbase * 5 + k];
  for (int j = tid; j < M_SZ; j += 256) {
    float4 g = gtb[j]; sg[j] = g; ga[j] = area_fn(g); scol[j] = 0ull;
  }
  if (tid < 64) srow[tid] = 0ull;
  __syncthreads();
  if (tid < 64) {
    const int i = pbase + tid;
    const float* sr = ssc + tid * C_SZ;
    float mx = sr[0]; int mi = 0;
    for (int j = 1; j < C_SZ; ++j) { float v = sr[j]; if (v > mx) { mx = v; mi = j; } }
    float s = 0.0f;
    for (int j = 0; j < C_SZ; ++j) s += expf(sr[j] - mx);
    lse[i] = mx + logf(s);
    // 16B-aligned gather: (84*i + 4*mi) floats is a multiple of 4 floats.
    float4 d = *(const float4*)(deltas + (size_t)i * (4 * C_SZ) + 4 * mi);
    const float* r = sro + tid * 5;
    float4 pb;
    pb.x = r[1] + d.x; pb.y = r[2] + d.y; pb.z = r[3] + d.z; pb.w = r[4] + d.w;
    spred[tid] = pb; sarea[tid] = area_fn(pb);
    pred[i] = pb;
  }
  __syncthreads();
  // --- micro-tile: 4 preds (regs) x 32 gts per thread; each IoU computed ONCE ---
  const int pg = tid & 15;
  const int gg = tid >> 4;
  const int p0 = pg << 2;
  const float4 pb0 = spred[p0 + 0], pb1 = spred[p0 + 1];
  const float4 pb2 = spred[p0 + 2], pb3 = spred[p0 + 3];
  const float pa0 = sarea[p0 + 0], pa1 = sarea[p0 + 1];
  const float pa2 = sarea[p0 + 2], pa3 = sarea[p0 + 3];
  const u32 cl0 = 0xFFFFFFFFu - (u32)(pbase + p0 + 0);
  const u32 cl1 = 0xFFFFFFFFu - (u32)(pbase + p0 + 1);
  const u32 cl2 = 0xFFFFFFFFu - (u32)(pbase + p0 + 2);
  const u32 cl3 = 0xFFFFFFFFu - (u32)(pbase + p0 + 3);
  u64 rk0 = 0ull, rk1 = 0ull, rk2 = 0ull, rk3 = 0ull;
  const int jbase = gg << 5;
  const int joff = (pg << 1);  // stagger: 16 pred-group threads hit 16 distinct j
#pragma unroll 2
  for (int jj = 0; jj < 32; ++jj) {
    const int j = jbase + ((jj + joff) & 31);
    const float4 gb = sg[j];
    const float gba = ga[j];
    const u32 lowj = 0xFFFFFFFFu - (u32)j;
    float v0 = iou_rcp(pb0, gb, pa0, gba);
    float v1 = iou_rcp(pb1, gb, pa1, gba);
    float v2 = iou_rcp(pb2, gb, pa2, gba);
    float v3 = iou_rcp(pb3, gb, pa3, gba);
    u64 k0 = ((u64)__float_as_uint(v0) << 32) | lowj; if (k0 > rk0) rk0 = k0;
    u64 k1 = ((u64)__float_as_uint(v1) << 32) | lowj; if (k1 > rk1) rk1 = k1;
    u64 k2 = ((u64)__float_as_uint(v2) << 32) | lowj; if (k2 > rk2) rk2 = k2;
    u64 k3 = ((u64)__float_as_uint(v3) << 32) | lowj; if (k3 > rk3) rk3 = k3;
    // col max among the 4 owned preds; equal-iou tie -> smaller pred idx (larger low32)
    u64 c = ((u64)__float_as_uint(v0) << 32) | cl0;
    u64 t1 = ((u64)__float_as_uint(v1) << 32) | cl1; if (t1 > c) c = t1;
    u64 t2 = ((u64)__float_as_uint(v2) << 32) | cl2; if (t2 > c) c = t2;
    u64 t3 = ((u64)__float_as_uint(v3) << 32) | cl3; if (t3 > c) c = t3;
    atomicMax(&scol[j], c);
  }
  atomicMax(&srow[p0 + 0], rk0);
  atomicMax(&srow[p0 + 1], rk1);
  atomicMax(&srow[p0 + 2], rk2);
  atomicMax(&srow[p0 + 3], rk3);
  __syncthreads();
  if (tid < 64) rowkey[pbase + tid] = srow[tid];
  for (int j = tid; j < M_SZ; j += 256) atomicMax(&gkey[j], scol[j]);
}

// ======== kB: scat + match + pos CE + bucket-store + wave-parallel prefix + compaction
//             + (block 255) negative selection. 256 blocks (1/CU, all co-resident).
__global__ void __launch_bounds__(256) kB(const u64* __restrict__ rowkey,
    const u64* __restrict__ gkey, const int* __restrict__ gtc,
    const float* __restrict__ scores, const float* __restrict__ lse,
    const float4* __restrict__ pred, const float4* __restrict__ gtb,
    u32* __restrict__ neg_u, u32* __restrict__ hist0, u64* __restrict__ bins,
    u64* __restrict__ scanst, float4* __restrict__ pp, float4* __restrict__ gp,
    State* st) {
  __shared__ int sscat[256];   // reused as scan buffer in selection
  __shared__ int swsum[4], sncnt[4];
  __shared__ double sdacc[4];
  __shared__ int s_bpref, s_np, s_nn, s_cp;
  __shared__ int s_d, s_kk, s_cnt;
  __shared__ u32 s_ovf;
  __shared__ u64 sth;
  __shared__ u64 scand[OVF_CAP];
  const int tid = threadIdx.x, b = blockIdx.x;
  const int lane = tid & 63, wid = tid >> 6;
  // ---- phase 1: rebuild scatter table for this block's pred range ----
  sscat[tid] = -1;
  __syncthreads();
  for (int g = tid; g < M_SZ; g += 256) {
    u64 key = gkey[g];
    int pidx = (int)(0xFFFFFFFFu - (u32)key);
    if ((pidx >> 8) == b) atomicMax(&sscat[pidx & 255], g);  // dup idx_g: last (max g) wins
  }
  __syncthreads();
  // ---- phase 2: match + per-i work ----
  const int i = (b << 8) + tid;
  u64 rk = rowkey[i];
  float best = __uint_as_float((u32)(rk >> 32));
  int idxp = (int)(0xFFFFFFFFu - (u32)rk);
  int m;
  if (best < F_LOWER) m = -2;
  else {
    int s = sscat[tid];
    m = (s >= 0) ? s : ((best >= F_UPPER) ? idxp : -1);
  }
  u32 ub = threefry_bits((u32)i, L_SZ >> 1) >> 9;
  atomicExch(&neg_u[i], (m == -2) ? ub : 0xFFFFFFFFu);  // device-scope store
  float ce = 0.0f;
  if (m >= 0) {
    ce = lse[i] - scores[(size_t)i * C_SZ + gtc[m]];
  } else if (m == -2) {
    u32 bin = ub >> 10;
    u32 pos = atomicAdd(&hist0[bin], 1u);
    if (pos < BIN_CAP) atomicExch(&bins[(size_t)bin * BIN_CAP + pos], ((u64)ub << 16) | (u32)i);
  }
  u64 balp = __ballot(m >= 0);
  u64 baln = __ballot(m == -2);
  double acc = (double)ce;
  for (int off = 32; off > 0; off >>= 1) acc += __shfl_down(acc, off, 64);
  if (lane == 0) { swsum[wid] = __popcll(balp); sncnt[wid] = __popcll(baln); sdacc[wid] = acc; }
  __syncthreads();
  // ---- phase 3: publish aggregate; wave 0 sums predecessors 64-at-a-time ----
  if (tid == 0) {
    int cp = swsum[0] + swsum[1] + swsum[2] + swsum[3];
    int cn = sncnt[0] + sncnt[1] + sncnt[2] + sncnt[3];
    s_cp = cp;
    atomicAdd(&st->num_pos, cp);
    atomicAdd(&st->num_neg, cn);
    atomicAdd(&st->sum_pos_ce, sdacc[0] + sdacc[1] + sdacc[2] + sdacc[3]);
    __hip_atomic_store(&scanst[b], FLG_AGG | (u64)cp, __ATOMIC_RELEASE, __HIP_MEMORY_SCOPE_AGENT);
  }
  __syncthreads();
  if (wid == 0) {
    u64 runl = 0;
    for (int x = b - 1 - lane; x >= 0; x -= 64) {
      u64 v;
      do { v = ald64(&scanst[x]); } while (v == 0ull);  // all blocks publish AGG promptly
      runl += v & ~FLG_MASK;
    }
    for (int off = 32; off > 0; off >>= 1) runl += __shfl_down(runl, off, 64);
    if (lane == 0) {
      s_bpref = (int)runl;
      if (b == 255) {
        s_np = (int)runl + s_cp;   // total positives (deterministic)
        s_nn = aldi(&st->num_neg); // all publishers' adds visible via acquire loads
      }
    }
  }
  __syncthreads();
  // ---- phase 4: index-ordered compaction ----
  const int bpref = s_bpref;
  if (bpref < MAX_POS) {  // block-uniform
    int flag = (m >= 0) ? 1 : 0;
    int incl = flag;
#pragma unroll
    for (int off = 1; off < 64; off <<= 1) {
      int v = __shfl_up(incl, off, 64);
      if (lane >= off) incl += v;
    }
    if (lane == 63) swsum[wid] = incl;
    __syncthreads();
    int wbase = 0;
    for (int w = 0; w < wid; ++w) wbase += swsum[w];
    int rank = bpref + wbase + incl - flag;
    if (flag && rank < MAX_POS) { pp[rank] = pred[i]; gp[rank] = gtb[m]; }
  }
  // ---- phase 5: negative selection (block 255 only) ----
  if (b != 255) return;
  __syncthreads();
  const int np = s_np, nn = s_nn;  // bg_num = round(np * 1.0) = np
  if (np >= nn) {
    if (tid == 0) st->thresh = ~0ull;  // select all negatives
    return;
  }
  u32 loc[32]; int tsum = 0;
#pragma unroll
  for (int r = 0; r < 32; ++r) { loc[r] = ald32(&hist0[tid * 32 + r]); tsum += (int)loc[r]; }
  sscat[tid] = tsum;
  __syncthreads();
  for (int off = 1; off < 256; off <<= 1) {
    int v = (tid >= off) ? sscat[tid - off] : 0;
    __syncthreads();
    sscat[tid] += v;
    __syncthreads();
  }
  int incl2 = sscat[tid], excl2 = incl2 - tsum;
  if (np >= excl2 && np < incl2) {
    int kk = np - excl2; int d = 0, c = 0;
#pragma unroll
    for (int r = 0; r < 32; ++r) {
      if (kk < (int)loc[r]) { d = tid * 32 + r; c = (int)loc[r]; break; }
      kk -= (int)loc[r];
    }
    s_d = d; s_kk = kk; s_cnt = c;
  }
  if (tid == 0) s_ovf = 0;
  __syncthreads();
  const int d = s_d, kk = s_kk, cnt = s_cnt;
  if (cnt <= BIN_CAP) {
    if (tid < cnt) scand[tid] = ald64(&bins[(size_t)d * BIN_CAP + tid]);
    __syncthreads();
    if (tid < cnt) {
      u64 key = scand[tid];
      int rank = 0;
      for (int u = 0; u < cnt; ++u) rank += (scand[u] < key) ? 1 : 0;
      if (rank == kk) sth = key;  // keys unique -> single writer
    }
  } else {
    // fallback (Poisson(8) > 32: ~1e-12 per bin): sweep neg_u for bin-d keys
    for (int t = tid; t < L_SZ; t += 256) {
      u32 u = ald32(&neg_u[t]);
      if (u != 0xFFFFFFFFu && (int)(u >> 10) == d) {
        u32 pos = atomicAdd(&s_ovf, 1u);
        if (pos < OVF_CAP) scand[pos] = ((u64)u << 16) | (u32)t;
      }
    }
    __syncthreads();
    int c2 = (int)s_ovf; if (c2 > OVF_CAP) c2 = OVF_CAP;
    for (int t = tid; t < c2; t += 256) {
      u64 key = scand[t];
      int rank = 0;
      for (int u = 0; u < c2; ++u) rank += (scand[u] < key) ? 1 : 0;
      if (rank == kk) sth = key;
    }
  }
  __syncthreads();
  if (tid == 0) st->thresh = sth;  // select keys strictly below the rank-bg_num key
}

// ======== kC: neg CE (all 256 blocks) + pair smooth-L1 (blocks 0..127) + final write.
__global__ void __launch_bounds__(256) kC(const u32* __restrict__ neg_u,
    const float* __restrict__ scores, const float* __restrict__ lse,
    const float4* __restrict__ pp, const float4* __restrict__ gp,
    State* st, float* __restrict__ out) {
  __shared__ float4 sj[128];
  __shared__ double sdacc[4];
  const int tid = threadIdx.x, b = blockIdx.x;
  const int lane = tid & 63, wid = tid >> 6;
  const u64 thresh = st->thresh;
  const int i = (b << 8) + tid;
  u32 u = neg_u[i];
  double acc = 0.0;
  if (u != 0xFFFFFFFFu) {
    u64 key = ((u64)u << 16) | (u32)i;
    if (key < thresh)
      acc = (double)(lse[i] - scores[(size_t)i * C_SZ + (C_SZ - 1)]);  // BACKGROUND=20
  }
  for (int off = 32; off > 0; off >>= 1) acc += __shfl_down(acc, off, 64);
  if (lane == 0) sdacc[wid] = acc;
  __syncthreads();
  if (tid == 0) atomicAdd(&st->sum_neg_ce, sdacc[0] + sdacc[1] + sdacc[2] + sdacc[3]);
  __syncthreads();
  if (b < 128) {
    int n = st->num_pos; if (n > MAX_POS) n = MAX_POS;
    const int jb = (b & 15) << 7;
    if (tid < 128) {
      int j = jb + tid;
      sj[tid] = (j < n) ? pp[j] : make_float4(0.f, 0.f, 0.f, 0.f);
    }
    __syncthreads();
    const int ii = ((b >> 4) << 8) + tid;
    double pacc = 0.0;
    if (ii < n) {
      float4 g = gp[ii];
      int jend = n - jb; if (jend > 128) jend = 128;
      for (int j = 0; j < jend; ++j) {
        float4 p4 = sj[j];
        pacc += (double)sl1(p4.x - g.x);
        pacc += (double)sl1(p4.y - g.y);
        pacc += (double)sl1(p4.z - g.z);
        pacc += (double)sl1(p4.w - g.w);
      }
    }
    for (int off = 32; off > 0; off >>= 1) pacc += __shfl_down(pacc, off, 64);
    if (lane == 0) sdacc[wid] = pacc;
    __syncthreads();
    if (tid == 0) atomicAdd(&st->bbox_sum, sdacc[0] + sdacc[1] + sdacc[2] + sdacc[3]);
  }
  if (tid == 0) {
    __threadfence();
    u32 dn = atomicAdd(&st->done, 1u);
    if (dn == 255) {  // last block: all contributions at coherent point
      int np = aldi(&st->num_pos), nn = aldi(&st->num_neg);
      double spc = aldd(&st->sum_pos_ce), snc = aldd(&st->sum_neg_ce);
      double bbs = aldd(&st->bbox_sum);
      int nsel = (np < nn) ? np : nn;
      double wsum = (double)(np + nsel);
      out[0] = (float)((spc + snc) / wsum);
      out[1] = (float)bbs;
    }
  }
}

// ---------- launch ----------

extern "C" void kernel_launch(void* const* d_in, const int* in_sizes, int n_in,
                              void* d_out, int out_size, void* d_ws, size_t ws_size,
                              hipStream_t stream) {
  const float* rois   = (const float*)d_in[0];
  const float* scores = (const float*)d_in[1];
  const float* deltas = (const float*)d_in[2];
  const float4* gtb   = (const float4*)d_in[3];
  const int*   gtc    = (const int*)d_in[4];
  float* out = (float*)d_out;

  char* w = (char*)d_ws;
  // zero-init region: State | gkey | hist0 | scanst (~39KB memset)
  State* st    = (State*)w;   w += 256;
  u64* gkey    = (u64*)w;     w += (size_t)M_SZ * 8;
  u32* hist0   = (u32*)w;     w += (size_t)NBINS * 4;
  u64* scanst  = (u64*)w;     w += 256 * 8;
  char* zero_end = w;
  // no-init scratch
  u64* bins    = (u64*)w;     w += (size_t)NBINS * BIN_CAP * 8;
  float4* pred = (float4*)w;  w += (size_t)L_SZ * 16;
  float* lse   = (float*)w;   w += (size_t)L_SZ * 4;
  u64* rowkey  = (u64*)w;     w += (size_t)L_SZ * 8;
  u32* neg_u   = (u32*)w;     w += (size_t)L_SZ * 4;
  float4* pp   = (float4*)w;  w += (size_t)MAX_POS * 16;
  float4* gp   = (float4*)w;  w += (size_t)MAX_POS * 16;

  hipMemsetAsync(d_ws, 0, (size_t)(zero_end - (char*)d_ws), stream);

  kA<<<L_SZ / 64, 256, 0, stream>>>(rois, scores, deltas, gtb, pred, lse, rowkey, gkey);
  kB<<<L_SZ / 256, 256, 0, stream>>>(rowkey, gkey, gtc, scores, lse, pred, gtb,
                                     neg_u, hist0, bins, scanst, pp, gp, st);
  kC<<<L_SZ / 256, 256, 0, stream>>>(neg_u, scores, lse, pp, gp, st, out);
}